// Round 5
// baseline (639.450 us; speedup 1.0000x reference)
//
#include <hip/hip_runtime.h>
#include <math.h>

#define T_ 2048
#define D_ 2048
#define H_ 16
#define KVH_ 4
#define HD_ 128
#define E_ 8
#define I_ 1024
#define NQ_ 2048   // H_*HD_
#define NKV_ 512   // KVH_*HD_
#define QKVW_ 3072 // NQ_ + 2*NKV_

typedef unsigned short ushort_t;
typedef unsigned int uint_t;
typedef __attribute__((ext_vector_type(8))) short short8;
typedef __attribute__((ext_vector_type(4))) float f4v;

__device__ __forceinline__ ushort_t f2b(float x) {
  union { float f; uint_t u; } v; v.f = x;
  uint_t r = v.u + 0x7FFFu + ((v.u >> 16) & 1u);
  return (ushort_t)(r >> 16);
}
__device__ __forceinline__ float b2f(ushort_t b) {
  union { uint_t u; float f; } v; v.u = ((uint_t)b) << 16;
  return v.f;
}

#define GLD_LDS16(gp, lp)                                                      \
  __builtin_amdgcn_global_load_lds(                                            \
      (const __attribute__((address_space(1))) uint_t*)(gp),                   \
      (__attribute__((address_space(3))) uint_t*)(lp), 16, 0, 0)

// ---------------- transpose + f32->bf16 convert: out[C x R] = in[R x C]^T ----
__global__ __launch_bounds__(256) void tcvt_k(const float* __restrict__ in,
                                              ushort_t* __restrict__ out,
                                              int R, int C, long inB, long outB) {
  in += (size_t)blockIdx.z * inB;
  out += (size_t)blockIdx.z * outB;
  __shared__ float tile[32][33];
  int r0 = blockIdx.y * 32, c0 = blockIdx.x * 32;
  int tr = threadIdx.x >> 3, tc = (threadIdx.x & 7) * 4;
  float4 v = *(const float4*)&in[(size_t)(r0 + tr) * C + c0 + tc];
  tile[tr][tc] = v.x; tile[tr][tc + 1] = v.y;
  tile[tr][tc + 2] = v.z; tile[tr][tc + 3] = v.w;
  __syncthreads();
  ushort4 o;
  o.x = f2b(tile[tc + 0][tr]); o.y = f2b(tile[tc + 1][tr]);
  o.z = f2b(tile[tc + 2][tr]); o.w = f2b(tile[tc + 3][tr]);
  *(ushort4*)&out[(size_t)(c0 + tr) * R + r0 + tc] = o;
}

// ---------------- bias concat [bq | bk | bv] -> 3072 ----------------
__global__ __launch_bounds__(256) void bias_concat_k(const float* __restrict__ bq,
                                                     const float* __restrict__ bk,
                                                     const float* __restrict__ bv,
                                                     float* __restrict__ bc) {
  int i = blockIdx.x * 256 + threadIdx.x;
  bc[i] = i < NQ_ ? bq[i] : (i < NQ_ + NKV_ ? bk[i - NQ_] : bv[i - NQ_ - NKV_]);
}

// ---------------- RMSNorm 1: bf16 out ----------------
__global__ __launch_bounds__(256) void rmsnorm_k(const float* __restrict__ x,
                                                 const float* __restrict__ w,
                                                 ushort_t* __restrict__ yb) {
  int t = blockIdx.x;
  int tid = threadIdx.x;
  const float* xr = x + (size_t)t * D_;
  float4 a = *(const float4*)&xr[tid * 8];
  float4 b = *(const float4*)&xr[tid * 8 + 4];
  float v[8] = {a.x, a.y, a.z, a.w, b.x, b.y, b.z, b.w};
  float ss = 0.f;
#pragma unroll
  for (int i = 0; i < 8; i++) ss += v[i] * v[i];
#pragma unroll
  for (int off = 32; off >= 1; off >>= 1) ss += __shfl_xor(ss, off, 64);
  __shared__ float part[4];
  __shared__ float scsh;
  if ((tid & 63) == 0) part[tid >> 6] = ss;
  __syncthreads();
  if (tid == 0) scsh = rsqrtf((part[0] + part[1] + part[2] + part[3]) * (1.0f / D_) + 1e-6f);
  __syncthreads();
  float sc = scsh;
  float4 w0 = *(const float4*)&w[tid * 8];
  float4 w1 = *(const float4*)&w[tid * 8 + 4];
  float wv[8] = {w0.x, w0.y, w0.z, w0.w, w1.x, w1.y, w1.z, w1.w};
  ushort_t* ybr = yb + (size_t)t * D_;
  ushort4 p0, p1;
  p0.x = f2b(v[0] * sc * wv[0]); p0.y = f2b(v[1] * sc * wv[1]);
  p0.z = f2b(v[2] * sc * wv[2]); p0.w = f2b(v[3] * sc * wv[3]);
  p1.x = f2b(v[4] * sc * wv[4]); p1.y = f2b(v[5] * sc * wv[5]);
  p1.z = f2b(v[6] * sc * wv[6]); p1.w = f2b(v[7] * sc * wv[7]);
  *(ushort4*)&ybr[tid * 8] = p0;
  *(ushort4*)&ybr[tid * 8 + 4] = p1;
}

// ---------------- RMSNorm 2 + O-proj partial combine + residual ----------------
__global__ __launch_bounds__(256) void rms2_comb_k(const float* __restrict__ hs,
                                                   const ushort_t* __restrict__ Op0,
                                                   const ushort_t* __restrict__ Op1,
                                                   const float* __restrict__ w,
                                                   float* __restrict__ outh,
                                                   float* __restrict__ XN,
                                                   ushort_t* __restrict__ XNb) {
  int t = blockIdx.x;
  int tid = threadIdx.x;
  size_t base = (size_t)t * D_ + tid * 8;
  float4 a = *(const float4*)&hs[base];
  float4 b = *(const float4*)&hs[base + 4];
  ushort4 o00 = *(const ushort4*)&Op0[base];
  ushort4 o01 = *(const ushort4*)&Op0[base + 4];
  ushort4 o10 = *(const ushort4*)&Op1[base];
  ushort4 o11 = *(const ushort4*)&Op1[base + 4];
  float v[8];
  v[0] = a.x + b2f(o00.x) + b2f(o10.x);
  v[1] = a.y + b2f(o00.y) + b2f(o10.y);
  v[2] = a.z + b2f(o00.z) + b2f(o10.z);
  v[3] = a.w + b2f(o00.w) + b2f(o10.w);
  v[4] = b.x + b2f(o01.x) + b2f(o11.x);
  v[5] = b.y + b2f(o01.y) + b2f(o11.y);
  v[6] = b.z + b2f(o01.z) + b2f(o11.z);
  v[7] = b.w + b2f(o01.w) + b2f(o11.w);
  *(float4*)&outh[base] = make_float4(v[0], v[1], v[2], v[3]);
  *(float4*)&outh[base + 4] = make_float4(v[4], v[5], v[6], v[7]);
  float ss = 0.f;
#pragma unroll
  for (int i = 0; i < 8; i++) ss += v[i] * v[i];
#pragma unroll
  for (int off = 32; off >= 1; off >>= 1) ss += __shfl_xor(ss, off, 64);
  __shared__ float part[4];
  __shared__ float scsh;
  if ((tid & 63) == 0) part[tid >> 6] = ss;
  __syncthreads();
  if (tid == 0) scsh = rsqrtf((part[0] + part[1] + part[2] + part[3]) * (1.0f / D_) + 1e-6f);
  __syncthreads();
  float sc = scsh;
  float4 w0 = *(const float4*)&w[tid * 8];
  float4 w1 = *(const float4*)&w[tid * 8 + 4];
  float wv[8] = {w0.x, w0.y, w0.z, w0.w, w1.x, w1.y, w1.z, w1.w};
  float o[8];
#pragma unroll
  for (int i = 0; i < 8; i++) o[i] = v[i] * sc * wv[i];
  *(float4*)&XN[base] = make_float4(o[0], o[1], o[2], o[3]);
  *(float4*)&XN[base + 4] = make_float4(o[4], o[5], o[6], o[7]);
  ushort4 p0, p1;
  p0.x = f2b(o[0]); p0.y = f2b(o[1]); p0.z = f2b(o[2]); p0.w = f2b(o[3]);
  p1.x = f2b(o[4]); p1.y = f2b(o[5]); p1.z = f2b(o[6]); p1.w = f2b(o[7]);
  *(ushort4*)&XNb[base] = p0;
  *(ushort4*)&XNb[base + 4] = p1;
}

// ---------------- uniform bf16 MFMA GEMM, split-K x2, bf16 partial stores ----
// 128x128 tile, BK=32, 4 waves. 3-buffer LDS, depth-2 counted-vmcnt pipeline.
// GATH: A rows are token-indirect via ptok (fused gather for routed gate/up).
template <bool ROUTED, bool DUAL, bool GATH>
__global__ __launch_bounds__(256) void gemm2_k(
    const ushort_t* __restrict__ A, const ushort_t* __restrict__ BT0,
    const ushort_t* __restrict__ BT1, int Kd, int kLen, int N, long bExpStride,
    ushort_t* __restrict__ Ob0, ushort_t* __restrict__ Ob1, long partStride,
    const int* __restrict__ offs, const int* __restrict__ tlist,
    const int* __restrict__ ptok) {
  int bx = blockIdx.x;
  int ks = bx & 1;
  int ny = blockIdx.y;
  const ushort_t* BT = BT0;
  ushort_t* Ob = Ob0;
  if (DUAL) {
    int half = gridDim.y >> 1;
    if (ny >= half) { ny -= half; BT = BT1; Ob = Ob1; }
  }
  int n0 = ny * 128;
  int m0, off = 0, end = 0x7fffffff;
  if (ROUTED) {
    int ti = bx >> 1;
    if (ti >= tlist[40]) return;
    int pk = tlist[ti];
    int e = pk >> 8;
    m0 = (pk & 255) << 7;
    off = offs[e];
    end = offs[e + 1];
    BT += (size_t)e * bExpStride;
  } else {
    m0 = (bx >> 1) * 128;
  }
  Ob += (size_t)ks * partStride;
  int kOff = ks * kLen;
  __shared__ __align__(16) ushort_t As[3][128 * 32];
  __shared__ __align__(16) ushort_t Bs[3][128 * 32];
  int tid = threadIdx.x;
  int lane = tid & 63, w = tid >> 6;
  int r1 = tid >> 2, kc = (tid & 3) << 3;
  int s1 = off + m0 + r1, s2 = s1 + 64;
  if (ROUTED) {
    if (s1 > end - 1) s1 = end - 1;
    if (s2 > end - 1) s2 = end - 1;
  }
  int t1 = s1, t2 = s2;
  if (GATH) { t1 = ptok[s1]; t2 = ptok[s2]; }
  const ushort_t* gA1 = A + (size_t)t1 * Kd + kOff + kc;
  const ushort_t* gA2 = A + (size_t)t2 * Kd + kOff + kc;
  const ushort_t* gB1 = BT + (size_t)(n0 + r1) * Kd + kOff + kc;
  const ushort_t* gB2 = gB1 + (size_t)64 * Kd;
  int lOff = (tid & 192) * 8;
  f4v acc[4][4] = {};
  int ml = lane & 15, q = lane >> 4;
  int wm = (w & 1) << 6, wn = (w >> 1) << 6;
  int nk = kLen >> 5;  // >= 16 for all call sites
  // prologue: stage tiles 0 and 1
  GLD_LDS16(gA1, As[0] + lOff);
  GLD_LDS16(gA2, As[0] + lOff + 2048);
  GLD_LDS16(gB1, Bs[0] + lOff);
  GLD_LDS16(gB2, Bs[0] + lOff + 2048);
  GLD_LDS16(gA1 + 32, As[1] + lOff);
  GLD_LDS16(gA2 + 32, As[1] + lOff + 2048);
  GLD_LDS16(gB1 + 32, Bs[1] + lOff);
  GLD_LDS16(gB2 + 32, Bs[1] + lOff + 2048);
  int c0 = 0, c1 = 1, c2 = 2;
  for (int kt = 0; kt < nk - 1; ++kt) {
    asm volatile("s_waitcnt vmcnt(4)" ::: "memory");
    __builtin_amdgcn_s_barrier();
    __builtin_amdgcn_sched_barrier(0);
    if (kt + 2 < nk) {
      int k0 = (kt + 2) << 5;
      GLD_LDS16(gA1 + k0, As[c2] + lOff);
      GLD_LDS16(gA2 + k0, As[c2] + lOff + 2048);
      GLD_LDS16(gB1 + k0, Bs[c2] + lOff);
      GLD_LDS16(gB2 + k0, Bs[c2] + lOff + 2048);
    }
    const ushort_t* Ac = As[c0];
    const ushort_t* Bc = Bs[c0];
    short8 af[4], bf[4];
#pragma unroll
    for (int i = 0; i < 4; i++)
      af[i] = *(const short8*)&Ac[(wm + i * 16 + ml) * 32 + q * 8];
#pragma unroll
    for (int j = 0; j < 4; j++)
      bf[j] = *(const short8*)&Bc[(wn + j * 16 + ml) * 32 + q * 8];
#pragma unroll
    for (int i = 0; i < 4; i++)
#pragma unroll
      for (int j = 0; j < 4; j++)
        acc[i][j] = __builtin_amdgcn_mfma_f32_16x16x32_bf16(af[i], bf[j], acc[i][j], 0, 0, 0);
    int t = c0; c0 = c1; c1 = c2; c2 = t;
  }
  // last tile
  asm volatile("s_waitcnt vmcnt(0)" ::: "memory");
  __builtin_amdgcn_s_barrier();
  __builtin_amdgcn_sched_barrier(0);
  {
    const ushort_t* Ac = As[c0];
    const ushort_t* Bc = Bs[c0];
    short8 af[4], bf[4];
#pragma unroll
    for (int i = 0; i < 4; i++)
      af[i] = *(const short8*)&Ac[(wm + i * 16 + ml) * 32 + q * 8];
#pragma unroll
    for (int j = 0; j < 4; j++)
      bf[j] = *(const short8*)&Bc[(wn + j * 16 + ml) * 32 + q * 8];
#pragma unroll
    for (int i = 0; i < 4; i++)
#pragma unroll
      for (int j = 0; j < 4; j++)
        acc[i][j] = __builtin_amdgcn_mfma_f32_16x16x32_bf16(af[i], bf[j], acc[i][j], 0, 0, 0);
  }
#pragma unroll
  for (int i = 0; i < 4; i++) {
#pragma unroll
    for (int r = 0; r < 4; r++) {
      int row = off + m0 + wm + i * 16 + q * 4 + r;
      if (ROUTED && row >= end) continue;
      size_t base = (size_t)row * N + n0 + wn + ml;
#pragma unroll
      for (int j = 0; j < 4; j++) Ob[base + j * 16] = f2b(acc[i][j][r]);
    }
  }
}

// ---------------- QKV prep: partial sum + bias + RoPE + chunked layouts ----
__global__ __launch_bounds__(256) void qkv_prep_k(const ushort_t* __restrict__ P0,
                                                  const ushort_t* __restrict__ P1,
                                                  const float* __restrict__ biasC,
                                                  const int* __restrict__ pos,
                                                  ushort_t* __restrict__ Qbh,
                                                  ushort_t* __restrict__ Kbh,
                                                  ushort_t* __restrict__ Vth) {
  int t = blockIdx.x;
  int u = blockIdx.y * 4 + (threadIdx.x >> 6);
  int i = threadIdx.x & 63;
  int ts = t >> 6, tr = t & 63;
  const float scale = 0.08838834764831845f;
  size_t rowb = (size_t)t * QKVW_;
  if (u < 16) {  // Q head u: rope + scale
    int c1 = u * 128 + i, c2 = c1 + 64;
    float x1 = b2f(P0[rowb + c1]) + b2f(P1[rowb + c1]) + biasC[c1];
    float x2 = b2f(P0[rowb + c2]) + b2f(P1[rowb + c2]) + biasC[c2];
    float p = (float)pos[t];
    float f = p * expf(-0.21586735246819178f * (float)i);
    float sn, cs; sincosf(f, &sn, &cs);
    float o1 = (x1 * cs - x2 * sn) * scale;
    float o2 = (x2 * cs + x1 * sn) * scale;
    ushort_t* dst = Qbh + (size_t)u * (T_ * 128) + (size_t)ts * 8192;
    dst[(i >> 5) * 2048 + tr * 32 + (i & 31)] = f2b(o1);
    dst[((i + 64) >> 5) * 2048 + tr * 32 + (i & 31)] = f2b(o2);
  } else if (u < 20) {  // K head: rope
    int kvh = u - 16;
    int c1 = NQ_ + kvh * 128 + i, c2 = c1 + 64;
    float x1 = b2f(P0[rowb + c1]) + b2f(P1[rowb + c1]) + biasC[c1];
    float x2 = b2f(P0[rowb + c2]) + b2f(P1[rowb + c2]) + biasC[c2];
    float p = (float)pos[t];
    float f = p * expf(-0.21586735246819178f * (float)i);
    float sn, cs; sincosf(f, &sn, &cs);
    ushort_t* dst = Kbh + (size_t)kvh * (T_ * 128) + (size_t)ts * 8192;
    dst[(i >> 5) * 2048 + tr * 32 + (i & 31)] = f2b(x1 * cs - x2 * sn);
    dst[((i + 64) >> 5) * 2048 + tr * 32 + (i & 31)] = f2b(x2 * cs + x1 * sn);
  } else {  // V head: transpose
    int kvh = u - 20;
    int c1 = NQ_ + NKV_ + kvh * 128 + i, c2 = c1 + 64;
    float x1 = b2f(P0[rowb + c1]) + b2f(P1[rowb + c1]) + biasC[c1];
    float x2 = b2f(P0[rowb + c2]) + b2f(P1[rowb + c2]) + biasC[c2];
    ushort_t* dst = Vth + (size_t)kvh * (T_ * 128) + (size_t)ts * 8192;
    int base = (tr >> 5) * 4096 + (tr & 31);
    dst[base + i * 32] = f2b(x1);
    dst[base + (i + 64) * 32] = f2b(x2);
  }
}

// ---------------- MFMA causal GQA flash attention ----------------
// 2 waves/block, 32 q-rows per wave (2x16 groups) -> every K/V fragment read
// is shared by 2 row-groups in registers: per-step LDS traffic 80KB vs 136KB.
// Single-buffered K/V with split staging: K(st+1) issued after the QK-consumed
// barrier, V(st+1) after the PV-consumed barrier; counted vmcnt(8) keeps the
// other stream in flight. LDS 48KB -> 3 blocks/CU.
__global__ __launch_bounds__(128, 1) void attn2_k(const ushort_t* __restrict__ Qbh,
                                                  const ushort_t* __restrict__ Kbh,
                                                  const ushort_t* __restrict__ Vth,
                                                  ushort_t* __restrict__ O) {
  __shared__ __align__(16) ushort_t Qs[8192];  // Q tile; reused as per-wave P
  __shared__ __align__(16) ushort_t Ks[8192];
  __shared__ __align__(16) ushort_t Vs[8192];
  int idx = blockIdx.x;
  int h = idx & 15;
  int qt = (idx < 256) ? (idx >> 4) : (31 - ((idx - 256) >> 4));
  int kvh = h >> 2;
  int q0 = qt * 64;
  int tid = threadIdx.x;
  int w = tid >> 6, lane = tid & 63;
  int m = lane & 15, qd = lane >> 4;
  const ushort_t* kbase = Kbh + (size_t)kvh * (T_ * 128);
  const ushort_t* vbase = Vth + (size_t)kvh * (T_ * 128);
  int nst = qt + 1;
  // prologue: Q (8 GLD/wave), K0 (8), V0 (8)
  {
    const ushort_t* qsrc = Qbh + (size_t)h * (T_ * 128) + (size_t)qt * 8192 + w * 4096 + lane * 8;
    ushort_t* qdst = Qs + w * 4096;
#pragma unroll
    for (int i = 0; i < 8; i++) GLD_LDS16(qsrc + i * 512, qdst + i * 512);
    const ushort_t* ksp = kbase + w * 4096 + lane * 8;
    ushort_t* kd = Ks + w * 4096;
#pragma unroll
    for (int i = 0; i < 8; i++) GLD_LDS16(ksp + i * 512, kd + i * 512);
    const ushort_t* vsp = vbase + w * 4096 + lane * 8;
    ushort_t* vd = Vs + w * 4096;
#pragma unroll
    for (int i = 0; i < 8; i++) GLD_LDS16(vsp + i * 512, vd + i * 512);
  }
  asm volatile("s_waitcnt vmcnt(16)" ::: "memory");  // Q landed (own wave)
  __builtin_amdgcn_s_barrier();                      // Q landed (all waves)
  __builtin_amdgcn_sched_barrier(0);
  short8 qf[2][4];
#pragma unroll
  for (int g = 0; g < 2; g++)
#pragma unroll
    for (int kb = 0; kb < 4; kb++)
      qf[g][kb] = *(const short8*)&Qs[kb * 2048 + (w * 32 + g * 16 + m) * 32 + qd * 8];
  f4v o4[2][8] = {};
  float mrow[2][4], lrow[2][4];
#pragma unroll
  for (int g = 0; g < 2; g++)
#pragma unroll
    for (int r = 0; r < 4; r++) { mrow[g][r] = -INFINITY; lrow[g][r] = 0.f; }
  ushort_t* Pl = Qs + w * 2560;  // per-wave P strip [32][80] bf16 (16B-aligned rows)
  for (int st = 0; st < nst; st++) {
    asm volatile("s_waitcnt vmcnt(8)" ::: "memory");  // K(st) landed (own)
    __builtin_amdgcn_s_barrier();                     // K(st) landed (all)
    __builtin_amdgcn_sched_barrier(0);
    f4v s4[2][4] = {};
    __builtin_amdgcn_s_setprio(1);
#pragma unroll
    for (int j = 0; j < 4; j++) {
      short8 kf[4];
#pragma unroll
      for (int kb = 0; kb < 4; kb++)
        kf[kb] = *(const short8*)&Ks[kb * 2048 + (j * 16 + m) * 32 + qd * 8];
#pragma unroll
      for (int g = 0; g < 2; g++)
#pragma unroll
        for (int kb = 0; kb < 4; kb++)
          s4[g][j] = __builtin_amdgcn_mfma_f32_16x16x32_bf16(qf[g][kb], kf[kb], s4[g][j], 0, 0, 0);
    }
    __builtin_amdgcn_s_setprio(0);
    __builtin_amdgcn_s_barrier();  // all waves done reading Ks
    __builtin_amdgcn_sched_barrier(0);
    if (st + 1 < nst) {  // overwrite Ks with K(st+1); latency hides under softmax+PV
      const ushort_t* ksp = kbase + (size_t)(st + 1) * 8192 + w * 4096 + lane * 8;
      ushort_t* kd = Ks + w * 4096;
#pragma unroll
      for (int i = 0; i < 8; i++) GLD_LDS16(ksp + i * 512, kd + i * 512);
    }
    if (st == nst - 1) {
      int s0 = st * 64;
#pragma unroll
      for (int g = 0; g < 2; g++)
#pragma unroll
        for (int j = 0; j < 4; j++) {
          int col = s0 + j * 16 + m;
#pragma unroll
          for (int r = 0; r < 4; r++) {
            int row = q0 + w * 32 + g * 16 + qd * 4 + r;
            if (col > row) s4[g][j][r] = -INFINITY;
          }
        }
    }
    float alpha[2][4];
#pragma unroll
    for (int g = 0; g < 2; g++)
#pragma unroll
      for (int r = 0; r < 4; r++) {
        float mx = fmaxf(fmaxf(s4[g][0][r], s4[g][1][r]), fmaxf(s4[g][2][r], s4[g][3][r]));
#pragma unroll
        for (int off = 1; off < 16; off <<= 1) mx = fmaxf(mx, __shfl_xor(mx, off, 64));
        float mn = fmaxf(mrow[g][r], mx);
        alpha[g][r] = __expf(mrow[g][r] - mn);
        mrow[g][r] = mn;
        float ls = 0.f;
#pragma unroll
        for (int j = 0; j < 4; j++) {
          float p = __expf(s4[g][j][r] - mn);
          s4[g][j][r] = p;
          ls += p;
        }
#pragma unroll
        for (int off = 1; off < 16; off <<= 1) ls += __shfl_xor(ls, off, 64);
        lrow[g][r] = lrow[g][r] * alpha[g][r] + ls;
      }
    bool nochg = true;
#pragma unroll
    for (int g = 0; g < 2; g++)
#pragma unroll
      for (int r = 0; r < 4; r++) nochg &= (alpha[g][r] == 1.f);
    if (!__all((int)nochg)) {
#pragma unroll
      for (int g = 0; g < 2; g++)
#pragma unroll
        for (int jd = 0; jd < 8; jd++)
#pragma unroll
          for (int r = 0; r < 4; r++) o4[g][jd][r] *= alpha[g][r];
    }
#pragma unroll
    for (int g = 0; g < 2; g++)
#pragma unroll
      for (int j = 0; j < 4; j++)
#pragma unroll
        for (int r = 0; r < 4; r++)
          Pl[(g * 16 + qd * 4 + r) * 80 + j * 16 + m] = f2b(s4[g][j][r]);
    if (st + 1 < nst) {
      asm volatile("s_waitcnt vmcnt(8)" ::: "memory");  // V(st) landed (own)
    } else {
      asm volatile("s_waitcnt vmcnt(0)" ::: "memory");
    }
    __builtin_amdgcn_s_barrier();  // V(st) landed (all)
    __builtin_amdgcn_sched_barrier(0);
    short8 pf[2][2];
#pragma unroll
    for (int g = 0; g < 2; g++)
#pragma unroll
      for (int kb2 = 0; kb2 < 2; kb2++)
        pf[g][kb2] = *(const short8*)&Pl[(g * 16 + m) * 80 + kb2 * 32 + qd * 8];
    __builtin_amdgcn_s_setprio(1);
#pragma unroll
    for (int jd = 0; jd < 8; jd++) {
      short8 vf0 = *(const short8*)&Vs[(jd * 16 + m) * 32 + qd * 8];
      short8 vf1 = *(const short8*)&Vs[4096 + (jd * 16 + m) * 32 + qd * 8];
#pragma unroll
      for (int g = 0; g < 2; g++) {
        o4[g][jd] = __builtin_amdgcn_mfma_f32_16x16x32_bf16(pf[g][0], vf0, o4[g][jd], 0, 0, 0);
        o4[g][jd] = __builtin_amdgcn_mfma_f32_16x16x32_bf16(pf[g][1], vf1, o4[g][jd], 0, 0, 0);
      }
    }
    __builtin_amdgcn_s_setprio(0);
    __builtin_amdgcn_s_barrier();  // all waves done reading Vs
    __builtin_amdgcn_sched_barrier(0);
    if (st + 1 < nst) {  // overwrite Vs with V(st+1); latency hides under next QK+softmax
      const ushort_t* vsp = vbase + (size_t)(st + 1) * 8192 + w * 4096 + lane * 8;
      ushort_t* vd = Vs + w * 4096;
#pragma unroll
      for (int i = 0; i < 8; i++) GLD_LDS16(vsp + i * 512, vd + i * 512);
    }
  }
  float inv[2][4];
#pragma unroll
  for (int g = 0; g < 2; g++)
#pragma unroll
    for (int r = 0; r < 4; r++) inv[g][r] = 1.0f / lrow[g][r];
#pragma unroll
  for (int g = 0; g < 2; g++)
#pragma unroll
    for (int jd = 0; jd < 8; jd++)
#pragma unroll
      for (int r = 0; r < 4; r++) {
        int row = q0 + w * 32 + g * 16 + qd * 4 + r;
        O[(size_t)row * NQ_ + h * 128 + jd * 16 + m] = f2b(o4[g][jd][r] * inv[g][r]);
      }
}

// ---------------- router (f32 inputs -> exact top-2 vs reference) ----------------
__global__ __launch_bounds__(256) void router_k(const float* __restrict__ X,
                                                const float* __restrict__ GW,
                                                int* __restrict__ tids,
                                                float* __restrict__ tws) {
  int t = blockIdx.x;
  int tid = threadIdx.x;
  const float* xr = X + (size_t)t * D_ + tid * 8;
  float4 a = *(const float4*)xr;
  float4 b = *(const float4*)(xr + 4);
  float xv[8] = {a.x, a.y, a.z, a.w, b.x, b.y, b.z, b.w};
  float acc[8] = {};
  const float* g = GW + (size_t)tid * 64;
#pragma unroll
  for (int rrow = 0; rrow < 8; rrow++) {
    float4 g0 = *(const float4*)(g + rrow * 8);
    float4 g1 = *(const float4*)(g + rrow * 8 + 4);
    float xs = xv[rrow];
    acc[0] += xs * g0.x; acc[1] += xs * g0.y; acc[2] += xs * g0.z; acc[3] += xs * g0.w;
    acc[4] += xs * g1.x; acc[5] += xs * g1.y; acc[6] += xs * g1.z; acc[7] += xs * g1.w;
  }
#pragma unroll
  for (int e = 0; e < 8; e++)
#pragma unroll
    for (int off = 32; off >= 1; off >>= 1) acc[e] += __shfl_xor(acc[e], off, 64);
  __shared__ float part[4][8];
  if ((tid & 63) == 0)
#pragma unroll
    for (int e = 0; e < 8; e++) part[tid >> 6][e] = acc[e];
  __syncthreads();
  if (tid == 0) {
    float lg[8];
#pragma unroll
    for (int e = 0; e < 8; e++) lg[e] = part[0][e] + part[1][e] + part[2][e] + part[3][e];
    int i1 = 0;
    for (int e = 1; e < 8; e++) if (lg[e] > lg[i1]) i1 = e;
    int i2 = (i1 == 0) ? 1 : 0;
    for (int e = 0; e < 8; e++) if (e != i1 && lg[e] > lg[i2]) i2 = e;
    float e2 = expf(lg[i2] - lg[i1]);
    float s = 1.0f + e2;
    tids[t * 2] = i1; tids[t * 2 + 1] = i2;
    tws[t * 2] = 1.0f / s; tws[t * 2 + 1] = e2 / s;
  }
}

// ---------------- per-expert compacted slot lists + inverse map + tile list ----
__global__ __launch_bounds__(256) void route_build_k(const int* __restrict__ tids,
                                                     int* __restrict__ offs,
                                                     int* __restrict__ ptok,
                                                     int* __restrict__ sidx,
                                                     int* __restrict__ tlist) {
  __shared__ int cnt[8];
  __shared__ int cur[8];
  int tid = threadIdx.x;
  if (tid < 8) cnt[tid] = 0;
  __syncthreads();
  for (int s = tid; s < T_ * 2; s += 256) atomicAdd(&cnt[tids[s]], 1);
  __syncthreads();
  if (tid == 0) {
    int o = 0, nt = 0;
    for (int e = 0; e < 8; e++) {
      cur[e] = o; offs[e] = o; o += cnt[e];
      int nm = (cnt[e] + 127) >> 7;
      for (int m = 0; m < nm; m++) tlist[nt++] = (e << 8) | m;
    }
    offs[8] = o;
    tlist[40] = nt;  // nt <= 39
  }
  __syncthreads();
  for (int s = tid; s < T_ * 2; s += 256) {
    int e = tids[s];
    int p = atomicAdd(&cur[e], 1);
    ptok[p] = s >> 1;
    sidx[s] = p;
  }
}

// ---------------- SwiGLU over partial pairs: FF = silu(G0+G1) * (U0+U1) ----
__global__ __launch_bounds__(256) void swiglu_k(const ushort_t* __restrict__ Gp,
                                                const ushort_t* __restrict__ Up,
                                                ushort_t* __restrict__ FF) {
  const long PS = 4194304;  // 4096*1024
  long i = (long)(blockIdx.x * 256 + threadIdx.x) * 4;
  ushort4 g0 = *(const ushort4*)&Gp[i];
  ushort4 g1 = *(const ushort4*)&Gp[i + PS];
  ushort4 u0 = *(const ushort4*)&Up[i];
  ushort4 u1 = *(const ushort4*)&Up[i + PS];
  float g[4] = {b2f(g0.x) + b2f(g1.x), b2f(g0.y) + b2f(g1.y),
                b2f(g0.z) + b2f(g1.z), b2f(g0.w) + b2f(g1.w)};
  float u[4] = {b2f(u0.x) + b2f(u1.x), b2f(u0.y) + b2f(u1.y),
                b2f(u0.z) + b2f(u1.z), b2f(u0.w) + b2f(u1.w)};
  ushort4 o;
  o.x = f2b(g[0] / (1.f + __expf(-g[0])) * u[0]);
  o.y = f2b(g[1] / (1.f + __expf(-g[1])) * u[1]);
  o.z = f2b(g[2] / (1.f + __expf(-g[2])) * u[2]);
  o.w = f2b(g[3] / (1.f + __expf(-g[3])) * u[3]);
  *(ushort4*)&FF[i] = o;
}

// ---------------- MoE combine: out[t] += w0*Y[s0] + w1*Y[s1] (partial pairs) ----
__global__ __launch_bounds__(256) void moe_combine_k(const ushort_t* __restrict__ Yp,
                                                     const int* __restrict__ sidx,
                                                     const float* __restrict__ tws,
                                                     float* __restrict__ out) {
  const long PS = 8388608;  // 4096*2048
  int t = blockIdx.x;
  int s0 = sidx[t * 2], s1 = sidx[t * 2 + 1];
  float w0 = tws[t * 2], w1 = tws[t * 2 + 1];
  int c = threadIdx.x * 8;
  size_t ob = (size_t)t * D_ + c;
  const ushort_t* y00 = Yp + (size_t)s0 * D_ + c;
  const ushort_t* y10 = Yp + (size_t)s1 * D_ + c;
  float4 r0 = *(const float4*)&out[ob];
  float4 r1 = *(const float4*)&out[ob + 4];
  float acc[8] = {r0.x, r0.y, r0.z, r0.w, r1.x, r1.y, r1.z, r1.w};
  ushort4 a0 = *(const ushort4*)y00;
  ushort4 a1 = *(const ushort4*)(y00 + 4);
  ushort4 b0 = *(const ushort4*)(y00 + PS);
  ushort4 b1 = *(const ushort4*)(y00 + PS + 4);
  acc[0] += w0 * (b2f(a0.x) + b2f(b0.x)); acc[1] += w0 * (b2f(a0.y) + b2f(b0.y));
  acc[2] += w0 * (b2f(a0.z) + b2f(b0.z)); acc[3] += w0 * (b2f(a0.w) + b2f(b0.w));
  acc[4] += w0 * (b2f(a1.x) + b2f(b1.x)); acc[5] += w0 * (b2f(a1.y) + b2f(b1.y));
  acc[6] += w0 * (b2f(a1.z) + b2f(b1.z)); acc[7] += w0 * (b2f(a1.w) + b2f(b1.w));
  a0 = *(const ushort4*)y10;
  a1 = *(const ushort4*)(y10 + 4);
  b0 = *(const ushort4*)(y10 + PS);
  b1 = *(const ushort4*)(y10 + PS + 4);
  acc[0] += w1 * (b2f(a0.x) + b2f(b0.x)); acc[1] += w1 * (b2f(a0.y) + b2f(b0.y));
  acc[2] += w1 * (b2f(a0.z) + b2f(b0.z)); acc[3] += w1 * (b2f(a0.w) + b2f(b0.w));
  acc[4] += w1 * (b2f(a1.x) + b2f(b1.x)); acc[5] += w1 * (b2f(a1.y) + b2f(b1.y));
  acc[6] += w1 * (b2f(a1.z) + b2f(b1.z)); acc[7] += w1 * (b2f(a1.w) + b2f(b1.w));
  *(float4*)&out[ob] = make_float4(acc[0], acc[1], acc[2], acc[3]);
  *(float4*)&out[ob + 4] = make_float4(acc[4], acc[5], acc[6], acc[7]);
}

extern "C" void kernel_launch(void* const* d_in, const int* in_sizes, int n_in,
                              void* d_out, int out_size, void* d_ws, size_t ws_size,
                              hipStream_t stream) {
  const float* hs  = (const float*)d_in[0];
  const int*   pos = (const int*)d_in[1];
  const float* ln1 = (const float*)d_in[2];
  const float* ln2 = (const float*)d_in[3];
  const float* wq  = (const float*)d_in[4];
  const float* bq  = (const float*)d_in[5];
  const float* wk  = (const float*)d_in[6];
  const float* bk  = (const float*)d_in[7];
  const float* wv  = (const float*)d_in[8];
  const float* bvp = (const float*)d_in[9];
  const float* wo  = (const float*)d_in[10];
  const float* gw  = (const float*)d_in[11];
  const float* wg  = (const float*)d_in[12];
  const float* wu  = (const float*)d_in[13];
  const float* wd  = (const float*)d_in[14];
  float* out = (float*)d_out;

  const size_t M = 1048576;
  float* ws = (float*)d_ws;
  // ---- dynamic region [0, 14M floats), phase-overlapped ----
  ushort_t* XNb   = (ushort_t*)ws;                  // [0,2M) — rms out; live through gate/up gemm
  ushort_t* QKVp  = (ushort_t*)(ws + 2 * M);        // [2M,8M) — 2x 2048x3072 bf16
  ushort_t* Qbh   = (ushort_t*)(ws + 8 * M);        // [8M,10M)
  ushort_t* Kbh   = (ushort_t*)(ws + 10 * M);       // [10M,10.5M)
  ushort_t* Vth   = (ushort_t*)(ws + 10 * M + 524288); // [10.5M,11M)
  ushort_t* ATb   = (ushort_t*)(ws + 11 * M);       // [11M,13M)
  ushort_t* Op    = (ushort_t*)(ws + 2 * M);        // [2M,6M) — QKVp dead
  float*    XN    = ws + 6 * M;                     // [6M,10M) f32 — dead after router
  ushort_t* Gp    = (ushort_t*)(ws + 2 * M);        // [2M,6M) — Op dead at MoE
  ushort_t* Up    = (ushort_t*)(ws + 6 * M);        // [6M,10M) — XN dead
  ushort_t* FF    = (ushort_t*)(ws + 10 * M);       // [10M,12M) — K/V dead
  ushort_t* Yp    = (ushort_t*)ws;                  // [0,8M) — XNb/Gp/Up dead after swiglu
  // ---- persistent weights [14M, 43M) ----
  ushort_t* wqkvT = (ushort_t*)(ws + 14 * M);       // 3072x2048
  ushort_t* woT   = (ushort_t*)(ws + 17 * M);       // 2048x2048
  ushort_t* wgT   = (ushort_t*)(ws + 19 * M);       // 8x1024x2048
  ushort_t* wuT   = (ushort_t*)(ws + 27 * M);       // 8x1024x2048
  ushort_t* wdT   = (ushort_t*)(ws + 35 * M);       // 8x2048x1024
  // ---- small persistent [43M, ...) ----
  float*    biasC = ws + 43 * M;                    // 3072 f32
  int*      tids  = (int*)(biasC + 4096);
  float*    tws   = (float*)(tids + 4096);
  int*      offs  = (int*)(tws + 4096);
  int*      ptok  = offs + 16;
  int*      sidx  = ptok + 4096;
  int*      tlist = sidx + 4096;                    // 64 ints; [40] = count

  // ---- weight pre-pass: transpose + bf16 convert ----
  tcvt_k<<<dim3(64, 64, 1), 256, 0, stream>>>(wq, wqkvT, 2048, 2048, 0, 0);
  tcvt_k<<<dim3(16, 64, 1), 256, 0, stream>>>(wk, wqkvT + (size_t)2048 * 2048, 2048, 512, 0, 0);
  tcvt_k<<<dim3(16, 64, 1), 256, 0, stream>>>(wv, wqkvT + (size_t)2560 * 2048, 2048, 512, 0, 0);
  tcvt_k<<<dim3(64, 64, 1), 256, 0, stream>>>(wo, woT, 2048, 2048, 0, 0);
  tcvt_k<<<dim3(32, 64, 8), 256, 0, stream>>>(wg, wgT, 2048, 1024, 2048L * 1024, 2048L * 1024);
  tcvt_k<<<dim3(32, 64, 8), 256, 0, stream>>>(wu, wuT, 2048, 1024, 2048L * 1024, 2048L * 1024);
  tcvt_k<<<dim3(64, 32, 8), 256, 0, stream>>>(wd, wdT, 1024, 2048, 1024L * 2048, 1024L * 2048);
  bias_concat_k<<<12, 256, 0, stream>>>(bq, bk, bvp, biasC);

  // ---- layer ----
  rmsnorm_k<<<T_, 256, 0, stream>>>(hs, ln1, XNb);
  // QKV projection, split-K x2 -> bf16 partials
  gemm2_k<false, false, false><<<dim3(32, 24, 1), 256, 0, stream>>>(
      XNb, wqkvT, nullptr, D_, 1024, QKVW_, 0, QKVp, nullptr, (long)T_ * QKVW_,
      nullptr, nullptr, nullptr);
  qkv_prep_k<<<dim3(T_, 6), 256, 0, stream>>>(QKVp, QKVp + (size_t)T_ * QKVW_, biasC, pos,
                                              Qbh, Kbh, Vth);
  attn2_k<<<512, 128, 0, stream>>>(Qbh, Kbh, Vth, ATb);
  // O-projection, split-K x2 -> bf16 partials
  gemm2_k<false, false, false><<<dim3(32, 16, 1), 256, 0, stream>>>(
      ATb, woT, nullptr, NQ_, 1024, D_, 0, Op, nullptr, (long)T_ * D_,
      nullptr, nullptr, nullptr);
  // h = hs + Op0 + Op1 -> out; rmsnorm2 -> XN, XNb
  rms2_comb_k<<<T_, 256, 0, stream>>>(hs, Op, Op + (size_t)T_ * D_, ln2, out, XN, XNb);
  router_k<<<T_, 256, 0, stream>>>(XN, gw, tids, tws);
  route_build_k<<<1, 256, 0, stream>>>(tids, offs, ptok, sidx, tlist);
  // routed gate+up, split-K x2 (DUAL splits grid.y), gather fused via ptok
  gemm2_k<true, true, true><<<dim3(80, 16, 1), 256, 0, stream>>>(
      XNb, wgT, wuT, D_, 1024, I_, 1024L * 2048, Gp, Up, 4194304L, offs, tlist, ptok);
  swiglu_k<<<4096, 256, 0, stream>>>(Gp, Up, FF);
  // routed down-proj, split-K x2 -> bf16 partials (slot rows)
  gemm2_k<true, false, false><<<dim3(80, 16, 1), 256, 0, stream>>>(
      FF, wdT, nullptr, I_, 512, D_, 1024L * 2048, Yp, nullptr, 8388608L, offs, tlist, nullptr);
  moe_combine_k<<<T_, 256, 0, stream>>>(Yp, sidx, tws, out);
}

// Round 6
// 596.067 us; speedup vs baseline: 1.0728x; 1.0728x over previous
//
#include <hip/hip_runtime.h>
#include <math.h>

#define T_ 2048
#define D_ 2048
#define H_ 16
#define KVH_ 4
#define HD_ 128
#define E_ 8
#define I_ 1024
#define NQ_ 2048   // H_*HD_
#define NKV_ 512   // KVH_*HD_
#define QKVW_ 3072 // NQ_ + 2*NKV_

typedef unsigned short ushort_t;
typedef unsigned int uint_t;
typedef __attribute__((ext_vector_type(8))) short short8;
typedef __attribute__((ext_vector_type(4))) float f4v;

__device__ __forceinline__ ushort_t f2b(float x) {
  union { float f; uint_t u; } v; v.f = x;
  uint_t r = v.u + 0x7FFFu + ((v.u >> 16) & 1u);
  return (ushort_t)(r >> 16);
}
__device__ __forceinline__ float b2f(ushort_t b) {
  union { uint_t u; float f; } v; v.u = ((uint_t)b) << 16;
  return v.f;
}

#define GLD_LDS16(gp, lp)                                                      \
  __builtin_amdgcn_global_load_lds(                                            \
      (const __attribute__((address_space(1))) uint_t*)(gp),                   \
      (__attribute__((address_space(3))) uint_t*)(lp), 16, 0, 0)

// ---------------- transpose + f32->bf16 convert: out[C x R] = in[R x C]^T ----
__global__ __launch_bounds__(256) void tcvt_k(const float* __restrict__ in,
                                              ushort_t* __restrict__ out,
                                              int R, int C, long inB, long outB) {
  in += (size_t)blockIdx.z * inB;
  out += (size_t)blockIdx.z * outB;
  __shared__ float tile[32][33];
  int r0 = blockIdx.y * 32, c0 = blockIdx.x * 32;
  int tr = threadIdx.x >> 3, tc = (threadIdx.x & 7) * 4;
  float4 v = *(const float4*)&in[(size_t)(r0 + tr) * C + c0 + tc];
  tile[tr][tc] = v.x; tile[tr][tc + 1] = v.y;
  tile[tr][tc + 2] = v.z; tile[tr][tc + 3] = v.w;
  __syncthreads();
  ushort4 o;
  o.x = f2b(tile[tc + 0][tr]); o.y = f2b(tile[tc + 1][tr]);
  o.z = f2b(tile[tc + 2][tr]); o.w = f2b(tile[tc + 3][tr]);
  *(ushort4*)&out[(size_t)(c0 + tr) * R + r0 + tc] = o;
}

// ---------------- bias concat [bq | bk | bv] -> 3072 ----------------
__global__ __launch_bounds__(256) void bias_concat_k(const float* __restrict__ bq,
                                                     const float* __restrict__ bk,
                                                     const float* __restrict__ bv,
                                                     float* __restrict__ bc) {
  int i = blockIdx.x * 256 + threadIdx.x;
  bc[i] = i < NQ_ ? bq[i] : (i < NQ_ + NKV_ ? bk[i - NQ_] : bv[i - NQ_ - NKV_]);
}

// ---------------- RMSNorm 1: bf16 out ----------------
__global__ __launch_bounds__(256) void rmsnorm_k(const float* __restrict__ x,
                                                 const float* __restrict__ w,
                                                 ushort_t* __restrict__ yb) {
  int t = blockIdx.x;
  int tid = threadIdx.x;
  const float* xr = x + (size_t)t * D_;
  float4 a = *(const float4*)&xr[tid * 8];
  float4 b = *(const float4*)&xr[tid * 8 + 4];
  float v[8] = {a.x, a.y, a.z, a.w, b.x, b.y, b.z, b.w};
  float ss = 0.f;
#pragma unroll
  for (int i = 0; i < 8; i++) ss += v[i] * v[i];
#pragma unroll
  for (int off = 32; off >= 1; off >>= 1) ss += __shfl_xor(ss, off, 64);
  __shared__ float part[4];
  __shared__ float scsh;
  if ((tid & 63) == 0) part[tid >> 6] = ss;
  __syncthreads();
  if (tid == 0) scsh = rsqrtf((part[0] + part[1] + part[2] + part[3]) * (1.0f / D_) + 1e-6f);
  __syncthreads();
  float sc = scsh;
  float4 w0 = *(const float4*)&w[tid * 8];
  float4 w1 = *(const float4*)&w[tid * 8 + 4];
  float wv[8] = {w0.x, w0.y, w0.z, w0.w, w1.x, w1.y, w1.z, w1.w};
  ushort_t* ybr = yb + (size_t)t * D_;
  ushort4 p0, p1;
  p0.x = f2b(v[0] * sc * wv[0]); p0.y = f2b(v[1] * sc * wv[1]);
  p0.z = f2b(v[2] * sc * wv[2]); p0.w = f2b(v[3] * sc * wv[3]);
  p1.x = f2b(v[4] * sc * wv[4]); p1.y = f2b(v[5] * sc * wv[5]);
  p1.z = f2b(v[6] * sc * wv[6]); p1.w = f2b(v[7] * sc * wv[7]);
  *(ushort4*)&ybr[tid * 8] = p0;
  *(ushort4*)&ybr[tid * 8 + 4] = p1;
}

// ---------------- RMSNorm 2 + O-proj partial combine + residual ----------------
__global__ __launch_bounds__(256) void rms2_comb_k(const float* __restrict__ hs,
                                                   const ushort_t* __restrict__ Op0,
                                                   const ushort_t* __restrict__ Op1,
                                                   const float* __restrict__ w,
                                                   float* __restrict__ outh,
                                                   float* __restrict__ XN,
                                                   ushort_t* __restrict__ XNb) {
  int t = blockIdx.x;
  int tid = threadIdx.x;
  size_t base = (size_t)t * D_ + tid * 8;
  float4 a = *(const float4*)&hs[base];
  float4 b = *(const float4*)&hs[base + 4];
  ushort4 o00 = *(const ushort4*)&Op0[base];
  ushort4 o01 = *(const ushort4*)&Op0[base + 4];
  ushort4 o10 = *(const ushort4*)&Op1[base];
  ushort4 o11 = *(const ushort4*)&Op1[base + 4];
  float v[8];
  v[0] = a.x + b2f(o00.x) + b2f(o10.x);
  v[1] = a.y + b2f(o00.y) + b2f(o10.y);
  v[2] = a.z + b2f(o00.z) + b2f(o10.z);
  v[3] = a.w + b2f(o00.w) + b2f(o10.w);
  v[4] = b.x + b2f(o01.x) + b2f(o11.x);
  v[5] = b.y + b2f(o01.y) + b2f(o11.y);
  v[6] = b.z + b2f(o01.z) + b2f(o11.z);
  v[7] = b.w + b2f(o01.w) + b2f(o11.w);
  *(float4*)&outh[base] = make_float4(v[0], v[1], v[2], v[3]);
  *(float4*)&outh[base + 4] = make_float4(v[4], v[5], v[6], v[7]);
  float ss = 0.f;
#pragma unroll
  for (int i = 0; i < 8; i++) ss += v[i] * v[i];
#pragma unroll
  for (int off = 32; off >= 1; off >>= 1) ss += __shfl_xor(ss, off, 64);
  __shared__ float part[4];
  __shared__ float scsh;
  if ((tid & 63) == 0) part[tid >> 6] = ss;
  __syncthreads();
  if (tid == 0) scsh = rsqrtf((part[0] + part[1] + part[2] + part[3]) * (1.0f / D_) + 1e-6f);
  __syncthreads();
  float sc = scsh;
  float4 w0 = *(const float4*)&w[tid * 8];
  float4 w1 = *(const float4*)&w[tid * 8 + 4];
  float wv[8] = {w0.x, w0.y, w0.z, w0.w, w1.x, w1.y, w1.z, w1.w};
  float o[8];
#pragma unroll
  for (int i = 0; i < 8; i++) o[i] = v[i] * sc * wv[i];
  *(float4*)&XN[base] = make_float4(o[0], o[1], o[2], o[3]);
  *(float4*)&XN[base + 4] = make_float4(o[4], o[5], o[6], o[7]);
  ushort4 p0, p1;
  p0.x = f2b(o[0]); p0.y = f2b(o[1]); p0.z = f2b(o[2]); p0.w = f2b(o[3]);
  p1.x = f2b(o[4]); p1.y = f2b(o[5]); p1.z = f2b(o[6]); p1.w = f2b(o[7]);
  *(ushort4*)&XNb[base] = p0;
  *(ushort4*)&XNb[base + 4] = p1;
}

// ---------------- uniform bf16 MFMA GEMM, split-K x2, bf16 partial stores ----
// 128x128 tile, BK=32, 4 waves. 3-buffer LDS, depth-2 counted-vmcnt pipeline.
// Grid axes: blockIdx.x = n-panel (gridDim.x % 8 == 0 -> XCD = n-panel % 8,
// pinning all m-tiles of one B panel to one XCD's L2); blockIdx.y = (tile,ks).
// GATH: A rows are token-indirect via ptok (fused gather for routed gate/up).
template <bool ROUTED, bool DUAL, bool GATH>
__global__ __launch_bounds__(256) void gemm2_k(
    const ushort_t* __restrict__ A, const ushort_t* __restrict__ BT0,
    const ushort_t* __restrict__ BT1, int Kd, int kLen, int N, long bExpStride,
    ushort_t* __restrict__ Ob0, ushort_t* __restrict__ Ob1, long partStride,
    const int* __restrict__ offs, const int* __restrict__ tlist,
    const int* __restrict__ ptok) {
  int bx = blockIdx.y;  // (tile, ks)
  int ks = bx & 1;
  int ny = blockIdx.x;  // n-panel -> XCD affinity
  const ushort_t* BT = BT0;
  ushort_t* Ob = Ob0;
  if (DUAL) {
    int half = gridDim.x >> 1;
    if (ny >= half) { ny -= half; BT = BT1; Ob = Ob1; }
  }
  int n0 = ny * 128;
  int m0, off = 0, end = 0x7fffffff;
  if (ROUTED) {
    int ti = bx >> 1;
    if (ti >= tlist[40]) return;
    int pk = tlist[ti];
    int e = pk >> 8;
    m0 = (pk & 255) << 7;
    off = offs[e];
    end = offs[e + 1];
    BT += (size_t)e * bExpStride;
  } else {
    m0 = (bx >> 1) * 128;
  }
  Ob += (size_t)ks * partStride;
  int kOff = ks * kLen;
  __shared__ __align__(16) ushort_t As[3][128 * 32];
  __shared__ __align__(16) ushort_t Bs[3][128 * 32];
  int tid = threadIdx.x;
  int lane = tid & 63, w = tid >> 6;
  int r1 = tid >> 2, kc = (tid & 3) << 3;
  int s1 = off + m0 + r1, s2 = s1 + 64;
  if (ROUTED) {
    if (s1 > end - 1) s1 = end - 1;
    if (s2 > end - 1) s2 = end - 1;
  }
  int t1 = s1, t2 = s2;
  if (GATH) { t1 = ptok[s1]; t2 = ptok[s2]; }
  const ushort_t* gA1 = A + (size_t)t1 * Kd + kOff + kc;
  const ushort_t* gA2 = A + (size_t)t2 * Kd + kOff + kc;
  const ushort_t* gB1 = BT + (size_t)(n0 + r1) * Kd + kOff + kc;
  const ushort_t* gB2 = gB1 + (size_t)64 * Kd;
  int lOff = (tid & 192) * 8;
  f4v acc[4][4] = {};
  int ml = lane & 15, q = lane >> 4;
  int wm = (w & 1) << 6, wn = (w >> 1) << 6;
  int nk = kLen >> 5;  // >= 16 for all call sites
  // prologue: stage tiles 0 and 1
  GLD_LDS16(gA1, As[0] + lOff);
  GLD_LDS16(gA2, As[0] + lOff + 2048);
  GLD_LDS16(gB1, Bs[0] + lOff);
  GLD_LDS16(gB2, Bs[0] + lOff + 2048);
  GLD_LDS16(gA1 + 32, As[1] + lOff);
  GLD_LDS16(gA2 + 32, As[1] + lOff + 2048);
  GLD_LDS16(gB1 + 32, Bs[1] + lOff);
  GLD_LDS16(gB2 + 32, Bs[1] + lOff + 2048);
  int c0 = 0, c1 = 1, c2 = 2;
  for (int kt = 0; kt < nk - 1; ++kt) {
    asm volatile("s_waitcnt vmcnt(4)" ::: "memory");
    __builtin_amdgcn_s_barrier();
    __builtin_amdgcn_sched_barrier(0);
    if (kt + 2 < nk) {
      int k0 = (kt + 2) << 5;
      GLD_LDS16(gA1 + k0, As[c2] + lOff);
      GLD_LDS16(gA2 + k0, As[c2] + lOff + 2048);
      GLD_LDS16(gB1 + k0, Bs[c2] + lOff);
      GLD_LDS16(gB2 + k0, Bs[c2] + lOff + 2048);
    }
    const ushort_t* Ac = As[c0];
    const ushort_t* Bc = Bs[c0];
    short8 af[4], bf[4];
#pragma unroll
    for (int i = 0; i < 4; i++)
      af[i] = *(const short8*)&Ac[(wm + i * 16 + ml) * 32 + q * 8];
#pragma unroll
    for (int j = 0; j < 4; j++)
      bf[j] = *(const short8*)&Bc[(wn + j * 16 + ml) * 32 + q * 8];
#pragma unroll
    for (int i = 0; i < 4; i++)
#pragma unroll
      for (int j = 0; j < 4; j++)
        acc[i][j] = __builtin_amdgcn_mfma_f32_16x16x32_bf16(af[i], bf[j], acc[i][j], 0, 0, 0);
    int t = c0; c0 = c1; c1 = c2; c2 = t;
  }
  // last tile
  asm volatile("s_waitcnt vmcnt(0)" ::: "memory");
  __builtin_amdgcn_s_barrier();
  __builtin_amdgcn_sched_barrier(0);
  {
    const ushort_t* Ac = As[c0];
    const ushort_t* Bc = Bs[c0];
    short8 af[4], bf[4];
#pragma unroll
    for (int i = 0; i < 4; i++)
      af[i] = *(const short8*)&Ac[(wm + i * 16 + ml) * 32 + q * 8];
#pragma unroll
    for (int j = 0; j < 4; j++)
      bf[j] = *(const short8*)&Bc[(wn + j * 16 + ml) * 32 + q * 8];
#pragma unroll
    for (int i = 0; i < 4; i++)
#pragma unroll
      for (int j = 0; j < 4; j++)
        acc[i][j] = __builtin_amdgcn_mfma_f32_16x16x32_bf16(af[i], bf[j], acc[i][j], 0, 0, 0);
  }
#pragma unroll
  for (int i = 0; i < 4; i++) {
#pragma unroll
    for (int r = 0; r < 4; r++) {
      int row = off + m0 + wm + i * 16 + q * 4 + r;
      if (ROUTED && row >= end) continue;
      size_t base = (size_t)row * N + n0 + wn + ml;
#pragma unroll
      for (int j = 0; j < 4; j++) Ob[base + j * 16] = f2b(acc[i][j][r]);
    }
  }
}

// ---------------- QKV prep: partial sum + bias + RoPE + chunked layouts ----
__global__ __launch_bounds__(256) void qkv_prep_k(const ushort_t* __restrict__ P0,
                                                  const ushort_t* __restrict__ P1,
                                                  const float* __restrict__ biasC,
                                                  const int* __restrict__ pos,
                                                  ushort_t* __restrict__ Qbh,
                                                  ushort_t* __restrict__ Kbh,
                                                  ushort_t* __restrict__ Vth) {
  int t = blockIdx.x;
  int u = blockIdx.y * 4 + (threadIdx.x >> 6);
  int i = threadIdx.x & 63;
  int ts = t >> 6, tr = t & 63;
  const float scale = 0.08838834764831845f;
  size_t rowb = (size_t)t * QKVW_;
  if (u < 16) {  // Q head u: rope + scale
    int c1 = u * 128 + i, c2 = c1 + 64;
    float x1 = b2f(P0[rowb + c1]) + b2f(P1[rowb + c1]) + biasC[c1];
    float x2 = b2f(P0[rowb + c2]) + b2f(P1[rowb + c2]) + biasC[c2];
    float p = (float)pos[t];
    float f = p * expf(-0.21586735246819178f * (float)i);
    float sn, cs; sincosf(f, &sn, &cs);
    float o1 = (x1 * cs - x2 * sn) * scale;
    float o2 = (x2 * cs + x1 * sn) * scale;
    ushort_t* dst = Qbh + (size_t)u * (T_ * 128) + (size_t)ts * 8192;
    dst[(i >> 5) * 2048 + tr * 32 + (i & 31)] = f2b(o1);
    dst[((i + 64) >> 5) * 2048 + tr * 32 + (i & 31)] = f2b(o2);
  } else if (u < 20) {  // K head: rope
    int kvh = u - 16;
    int c1 = NQ_ + kvh * 128 + i, c2 = c1 + 64;
    float x1 = b2f(P0[rowb + c1]) + b2f(P1[rowb + c1]) + biasC[c1];
    float x2 = b2f(P0[rowb + c2]) + b2f(P1[rowb + c2]) + biasC[c2];
    float p = (float)pos[t];
    float f = p * expf(-0.21586735246819178f * (float)i);
    float sn, cs; sincosf(f, &sn, &cs);
    ushort_t* dst = Kbh + (size_t)kvh * (T_ * 128) + (size_t)ts * 8192;
    dst[(i >> 5) * 2048 + tr * 32 + (i & 31)] = f2b(x1 * cs - x2 * sn);
    dst[((i + 64) >> 5) * 2048 + tr * 32 + (i & 31)] = f2b(x2 * cs + x1 * sn);
  } else {  // V head: transpose
    int kvh = u - 20;
    int c1 = NQ_ + NKV_ + kvh * 128 + i, c2 = c1 + 64;
    float x1 = b2f(P0[rowb + c1]) + b2f(P1[rowb + c1]) + biasC[c1];
    float x2 = b2f(P0[rowb + c2]) + b2f(P1[rowb + c2]) + biasC[c2];
    ushort_t* dst = Vth + (size_t)kvh * (T_ * 128) + (size_t)ts * 8192;
    int base = (tr >> 5) * 4096 + (tr & 31);
    dst[base + i * 32] = f2b(x1);
    dst[base + (i + 64) * 32] = f2b(x2);
  }
}

// ---------------- MFMA causal GQA flash attention ----------------
// 2-phase counted pipeline: K/V double-buffered; stage(st+1) issued after the
// barrier, before compute(st); drained by vmcnt(0) at the NEXT iter's top, so
// L2 latency hides under QK^T+softmax+PV. One barrier per iteration.
__global__ __launch_bounds__(256) void attn2_k(const ushort_t* __restrict__ Qbh,
                                               const ushort_t* __restrict__ Kbh,
                                               const ushort_t* __restrict__ Vth,
                                               ushort_t* __restrict__ O) {
  __shared__ __align__(16) ushort_t Qs[8192];  // Q tile; reused as per-wave P
  __shared__ __align__(16) ushort_t Ks[2][8192];
  __shared__ __align__(16) ushort_t Vs[2][8192];
  int idx = blockIdx.x;
  int h = idx & 15;
  int qt = (idx < 256) ? (idx >> 4) : (31 - ((idx - 256) >> 4));
  int kvh = h >> 2;
  int q0 = qt * 64;
  int tid = threadIdx.x;
  int w = tid >> 6, lane = tid & 63;
  int m = lane & 15, qd = lane >> 4;
  const ushort_t* kbase = Kbh + (size_t)kvh * (T_ * 128);
  const ushort_t* vbase = Vth + (size_t)kvh * (T_ * 128);
  int nst = qt + 1;
  // prologue: Q loads (4/wave), then stage(0) K/V (8/wave)
  {
    const ushort_t* qsrc = Qbh + (size_t)h * (T_ * 128) + (size_t)qt * 8192 + w * 2048 + lane * 8;
    ushort_t* qdst = Qs + w * 2048;
#pragma unroll
    for (int i = 0; i < 4; i++) GLD_LDS16(qsrc + i * 512, qdst + i * 512);
  }
  {
    const ushort_t* ks = kbase + w * 2048 + lane * 8;
    const ushort_t* vs = vbase + w * 2048 + lane * 8;
    ushort_t* kd = Ks[0] + w * 2048;
    ushort_t* vd = Vs[0] + w * 2048;
#pragma unroll
    for (int i = 0; i < 4; i++) {
      GLD_LDS16(ks + i * 512, kd + i * 512);
      GLD_LDS16(vs + i * 512, vd + i * 512);
    }
  }
  asm volatile("s_waitcnt vmcnt(8)" ::: "memory");  // Q's 4 loads done
  __builtin_amdgcn_s_barrier();
  __builtin_amdgcn_sched_barrier(0);
  short8 qf[4];
#pragma unroll
  for (int kb = 0; kb < 4; kb++)
    qf[kb] = *(const short8*)&Qs[kb * 2048 + (w * 16 + m) * 32 + qd * 8];
  f4v o4[8] = {};
  float mrow[4], lrow[4];
#pragma unroll
  for (int r = 0; r < 4; r++) { mrow[r] = -INFINITY; lrow[r] = 0.f; }
  ushort_t* Pl = Qs + w * 2048;  // per-wave P strip [16][72] bf16 (wave-private)
  for (int st = 0; st < nst; st++) {
    int cur = st & 1;
    asm volatile("s_waitcnt vmcnt(0)" ::: "memory");  // stage(st) complete
    __builtin_amdgcn_s_barrier();
    __builtin_amdgcn_sched_barrier(0);
    if (st + 1 < nst) {  // stage(st+1) -> other buffer; drained next iter
      const ushort_t* ks = kbase + (size_t)(st + 1) * 8192 + w * 2048 + lane * 8;
      const ushort_t* vs = vbase + (size_t)(st + 1) * 8192 + w * 2048 + lane * 8;
      ushort_t* kd = Ks[cur ^ 1] + w * 2048;
      ushort_t* vd = Vs[cur ^ 1] + w * 2048;
#pragma unroll
      for (int i = 0; i < 4; i++) {
        GLD_LDS16(ks + i * 512, kd + i * 512);
        GLD_LDS16(vs + i * 512, vd + i * 512);
      }
    }
    f4v s4[4];
    __builtin_amdgcn_s_setprio(1);
#pragma unroll
    for (int j = 0; j < 4; j++) {
      f4v z = {};
      s4[j] = z;
#pragma unroll
      for (int kb = 0; kb < 4; kb++) {
        short8 kf = *(const short8*)&Ks[cur][kb * 2048 + (j * 16 + m) * 32 + qd * 8];
        s4[j] = __builtin_amdgcn_mfma_f32_16x16x32_bf16(qf[kb], kf, s4[j], 0, 0, 0);
      }
    }
    __builtin_amdgcn_s_setprio(0);
    if (st == nst - 1) {
      int s0 = st * 64;
#pragma unroll
      for (int j = 0; j < 4; j++) {
        int col = s0 + j * 16 + m;
#pragma unroll
        for (int r = 0; r < 4; r++) {
          int row = q0 + w * 16 + qd * 4 + r;
          if (col > row) s4[j][r] = -INFINITY;
        }
      }
    }
    float alpha[4];
#pragma unroll
    for (int r = 0; r < 4; r++) {
      float mx = fmaxf(fmaxf(s4[0][r], s4[1][r]), fmaxf(s4[2][r], s4[3][r]));
#pragma unroll
      for (int off = 1; off < 16; off <<= 1) mx = fmaxf(mx, __shfl_xor(mx, off, 64));
      float mn = fmaxf(mrow[r], mx);
      alpha[r] = __expf(mrow[r] - mn);
      mrow[r] = mn;
      float ls = 0.f;
#pragma unroll
      for (int j = 0; j < 4; j++) {
        float p = __expf(s4[j][r] - mn);
        s4[j][r] = p;
        ls += p;
      }
#pragma unroll
      for (int off = 1; off < 16; off <<= 1) ls += __shfl_xor(ls, off, 64);
      lrow[r] = lrow[r] * alpha[r] + ls;
    }
    // defer-rescale: skip the 32 mults when no lane's max moved (alpha==1 exact)
    bool nochg = (alpha[0] == 1.f) & (alpha[1] == 1.f) & (alpha[2] == 1.f) & (alpha[3] == 1.f);
    if (!__all((int)nochg)) {
#pragma unroll
      for (int jd = 0; jd < 8; jd++)
#pragma unroll
        for (int r = 0; r < 4; r++) o4[jd][r] *= alpha[r];
    }
#pragma unroll
    for (int j = 0; j < 4; j++)
#pragma unroll
      for (int r = 0; r < 4; r++)
        Pl[(qd * 4 + r) * 72 + j * 16 + m] = f2b(s4[j][r]);
    short8 pf[2];
#pragma unroll
    for (int kb2 = 0; kb2 < 2; kb2++)
      pf[kb2] = *(const short8*)&Pl[m * 72 + kb2 * 32 + qd * 8];
    __builtin_amdgcn_s_setprio(1);
#pragma unroll
    for (int jd = 0; jd < 8; jd++)
#pragma unroll
      for (int kb2 = 0; kb2 < 2; kb2++) {
        short8 vf = *(const short8*)&Vs[cur][kb2 * 4096 + (jd * 16 + m) * 32 + qd * 8];
        o4[jd] = __builtin_amdgcn_mfma_f32_16x16x32_bf16(pf[kb2], vf, o4[jd], 0, 0, 0);
      }
    __builtin_amdgcn_s_setprio(0);
  }
  float inv[4];
#pragma unroll
  for (int r = 0; r < 4; r++) inv[r] = 1.0f / lrow[r];
#pragma unroll
  for (int jd = 0; jd < 8; jd++)
#pragma unroll
    for (int r = 0; r < 4; r++) {
      int row = q0 + w * 16 + qd * 4 + r;
      O[(size_t)row * NQ_ + h * 128 + jd * 16 + m] = f2b(o4[jd][r] * inv[r]);
    }
}

// ---------------- router (f32 inputs -> exact top-2 vs reference) ----------------
__global__ __launch_bounds__(256) void router_k(const float* __restrict__ X,
                                                const float* __restrict__ GW,
                                                int* __restrict__ tids,
                                                float* __restrict__ tws) {
  int t = blockIdx.x;
  int tid = threadIdx.x;
  const float* xr = X + (size_t)t * D_ + tid * 8;
  float4 a = *(const float4*)xr;
  float4 b = *(const float4*)(xr + 4);
  float xv[8] = {a.x, a.y, a.z, a.w, b.x, b.y, b.z, b.w};
  float acc[8] = {};
  const float* g = GW + (size_t)tid * 64;
#pragma unroll
  for (int rrow = 0; rrow < 8; rrow++) {
    float4 g0 = *(const float4*)(g + rrow * 8);
    float4 g1 = *(const float4*)(g + rrow * 8 + 4);
    float xs = xv[rrow];
    acc[0] += xs * g0.x; acc[1] += xs * g0.y; acc[2] += xs * g0.z; acc[3] += xs * g0.w;
    acc[4] += xs * g1.x; acc[5] += xs * g1.y; acc[6] += xs * g1.z; acc[7] += xs * g1.w;
  }
#pragma unroll
  for (int e = 0; e < 8; e++)
#pragma unroll
    for (int off = 32; off >= 1; off >>= 1) acc[e] += __shfl_xor(acc[e], off, 64);
  __shared__ float part[4][8];
  if ((tid & 63) == 0)
#pragma unroll
    for (int e = 0; e < 8; e++) part[tid >> 6][e] = acc[e];
  __syncthreads();
  if (tid == 0) {
    float lg[8];
#pragma unroll
    for (int e = 0; e < 8; e++) lg[e] = part[0][e] + part[1][e] + part[2][e] + part[3][e];
    int i1 = 0;
    for (int e = 1; e < 8; e++) if (lg[e] > lg[i1]) i1 = e;
    int i2 = (i1 == 0) ? 1 : 0;
    for (int e = 0; e < 8; e++) if (e != i1 && lg[e] > lg[i2]) i2 = e;
    float e2 = expf(lg[i2] - lg[i1]);
    float s = 1.0f + e2;
    tids[t * 2] = i1; tids[t * 2 + 1] = i2;
    tws[t * 2] = 1.0f / s; tws[t * 2 + 1] = e2 / s;
  }
}

// ---------------- per-expert compacted slot lists + inverse map + tile list ----
__global__ __launch_bounds__(256) void route_build_k(const int* __restrict__ tids,
                                                     int* __restrict__ offs,
                                                     int* __restrict__ ptok,
                                                     int* __restrict__ sidx,
                                                     int* __restrict__ tlist) {
  __shared__ int cnt[8];
  __shared__ int cur[8];
  int tid = threadIdx.x;
  if (tid < 8) cnt[tid] = 0;
  __syncthreads();
  for (int s = tid; s < T_ * 2; s += 256) atomicAdd(&cnt[tids[s]], 1);
  __syncthreads();
  if (tid == 0) {
    int o = 0, nt = 0;
    for (int e = 0; e < 8; e++) {
      cur[e] = o; offs[e] = o; o += cnt[e];
      int nm = (cnt[e] + 127) >> 7;
      for (int m = 0; m < nm; m++) tlist[nt++] = (e << 8) | m;
    }
    offs[8] = o;
    tlist[40] = nt;  // nt <= 39
  }
  __syncthreads();
  for (int s = tid; s < T_ * 2; s += 256) {
    int e = tids[s];
    int p = atomicAdd(&cur[e], 1);
    ptok[p] = s >> 1;
    sidx[s] = p;
  }
}

// ---------------- SwiGLU over partial pairs: FF = silu(G0+G1) * (U0+U1) ----
__global__ __launch_bounds__(256) void swiglu_k(const ushort_t* __restrict__ Gp,
                                                const ushort_t* __restrict__ Up,
                                                ushort_t* __restrict__ FF) {
  const long PS = 4194304;  // 4096*1024
  long i = (long)(blockIdx.x * 256 + threadIdx.x) * 4;
  ushort4 g0 = *(const ushort4*)&Gp[i];
  ushort4 g1 = *(const ushort4*)&Gp[i + PS];
  ushort4 u0 = *(const ushort4*)&Up[i];
  ushort4 u1 = *(const ushort4*)&Up[i + PS];
  float g[4] = {b2f(g0.x) + b2f(g1.x), b2f(g0.y) + b2f(g1.y),
                b2f(g0.z) + b2f(g1.z), b2f(g0.w) + b2f(g1.w)};
  float u[4] = {b2f(u0.x) + b2f(u1.x), b2f(u0.y) + b2f(u1.y),
                b2f(u0.z) + b2f(u1.z), b2f(u0.w) + b2f(u1.w)};
  ushort4 o;
  o.x = f2b(g[0] / (1.f + __expf(-g[0])) * u[0]);
  o.y = f2b(g[1] / (1.f + __expf(-g[1])) * u[1]);
  o.z = f2b(g[2] / (1.f + __expf(-g[2])) * u[2]);
  o.w = f2b(g[3] / (1.f + __expf(-g[3])) * u[3]);
  *(ushort4*)&FF[i] = o;
}

// ---------------- MoE combine: out[t] += w0*Y[s0] + w1*Y[s1] (partial pairs) ----
__global__ __launch_bounds__(256) void moe_combine_k(const ushort_t* __restrict__ Yp,
                                                     const int* __restrict__ sidx,
                                                     const float* __restrict__ tws,
                                                     float* __restrict__ out) {
  const long PS = 8388608;  // 4096*2048
  int t = blockIdx.x;
  int s0 = sidx[t * 2], s1 = sidx[t * 2 + 1];
  float w0 = tws[t * 2], w1 = tws[t * 2 + 1];
  int c = threadIdx.x * 8;
  size_t ob = (size_t)t * D_ + c;
  const ushort_t* y00 = Yp + (size_t)s0 * D_ + c;
  const ushort_t* y10 = Yp + (size_t)s1 * D_ + c;
  float4 r0 = *(const float4*)&out[ob];
  float4 r1 = *(const float4*)&out[ob + 4];
  float acc[8] = {r0.x, r0.y, r0.z, r0.w, r1.x, r1.y, r1.z, r1.w};
  ushort4 a0 = *(const ushort4*)y00;
  ushort4 a1 = *(const ushort4*)(y00 + 4);
  ushort4 b0 = *(const ushort4*)(y00 + PS);
  ushort4 b1 = *(const ushort4*)(y00 + PS + 4);
  acc[0] += w0 * (b2f(a0.x) + b2f(b0.x)); acc[1] += w0 * (b2f(a0.y) + b2f(b0.y));
  acc[2] += w0 * (b2f(a0.z) + b2f(b0.z)); acc[3] += w0 * (b2f(a0.w) + b2f(b0.w));
  acc[4] += w0 * (b2f(a1.x) + b2f(b1.x)); acc[5] += w0 * (b2f(a1.y) + b2f(b1.y));
  acc[6] += w0 * (b2f(a1.z) + b2f(b1.z)); acc[7] += w0 * (b2f(a1.w) + b2f(b1.w));
  a0 = *(const ushort4*)y10;
  a1 = *(const ushort4*)(y10 + 4);
  b0 = *(const ushort4*)(y10 + PS);
  b1 = *(const ushort4*)(y10 + PS + 4);
  acc[0] += w1 * (b2f(a0.x) + b2f(b0.x)); acc[1] += w1 * (b2f(a0.y) + b2f(b0.y));
  acc[2] += w1 * (b2f(a0.z) + b2f(b0.z)); acc[3] += w1 * (b2f(a0.w) + b2f(b0.w));
  acc[4] += w1 * (b2f(a1.x) + b2f(b1.x)); acc[5] += w1 * (b2f(a1.y) + b2f(b1.y));
  acc[6] += w1 * (b2f(a1.z) + b2f(b1.z)); acc[7] += w1 * (b2f(a1.w) + b2f(b1.w));
  *(float4*)&out[ob] = make_float4(acc[0], acc[1], acc[2], acc[3]);
  *(float4*)&out[ob + 4] = make_float4(acc[4], acc[5], acc[6], acc[7]);
}

extern "C" void kernel_launch(void* const* d_in, const int* in_sizes, int n_in,
                              void* d_out, int out_size, void* d_ws, size_t ws_size,
                              hipStream_t stream) {
  const float* hs  = (const float*)d_in[0];
  const int*   pos = (const int*)d_in[1];
  const float* ln1 = (const float*)d_in[2];
  const float* ln2 = (const float*)d_in[3];
  const float* wq  = (const float*)d_in[4];
  const float* bq  = (const float*)d_in[5];
  const float* wk  = (const float*)d_in[6];
  const float* bk  = (const float*)d_in[7];
  const float* wv  = (const float*)d_in[8];
  const float* bvp = (const float*)d_in[9];
  const float* wo  = (const float*)d_in[10];
  const float* gw  = (const float*)d_in[11];
  const float* wg  = (const float*)d_in[12];
  const float* wu  = (const float*)d_in[13];
  const float* wd  = (const float*)d_in[14];
  float* out = (float*)d_out;

  const size_t M = 1048576;
  float* ws = (float*)d_ws;
  // ---- dynamic region [0, 14M floats), phase-overlapped ----
  ushort_t* XNb   = (ushort_t*)ws;                  // [0,2M) — rms out; live through gate/up gemm
  ushort_t* QKVp  = (ushort_t*)(ws + 2 * M);        // [2M,8M) — 2x 2048x3072 bf16
  ushort_t* Qbh   = (ushort_t*)(ws + 8 * M);        // [8M,10M)
  ushort_t* Kbh   = (ushort_t*)(ws + 10 * M);       // [10M,10.5M)
  ushort_t* Vth   = (ushort_t*)(ws + 10 * M + 524288); // [10.5M,11M)
  ushort_t* ATb   = (ushort_t*)(ws + 11 * M);       // [11M,13M)
  ushort_t* Op    = (ushort_t*)(ws + 2 * M);        // [2M,6M) — QKVp dead
  float*    XN    = ws + 6 * M;                     // [6M,10M) f32 — dead after router
  ushort_t* Gp    = (ushort_t*)(ws + 2 * M);        // [2M,6M) — Op dead at MoE
  ushort_t* Up    = (ushort_t*)(ws + 6 * M);        // [6M,10M) — XN dead
  ushort_t* FF    = (ushort_t*)(ws + 10 * M);       // [10M,12M) — K/V dead
  ushort_t* Yp    = (ushort_t*)ws;                  // [0,8M) — XNb/Gp/Up dead after swiglu
  // ---- persistent weights [14M, 43M) ----
  ushort_t* wqkvT = (ushort_t*)(ws + 14 * M);       // 3072x2048
  ushort_t* woT   = (ushort_t*)(ws + 17 * M);       // 2048x2048
  ushort_t* wgT   = (ushort_t*)(ws + 19 * M);       // 8x1024x2048
  ushort_t* wuT   = (ushort_t*)(ws + 27 * M);       // 8x1024x2048
  ushort_t* wdT   = (ushort_t*)(ws + 35 * M);       // 8x2048x1024
  // ---- small persistent [43M, ...) ----
  float*    biasC = ws + 43 * M;                    // 3072 f32
  int*      tids  = (int*)(biasC + 4096);
  float*    tws   = (float*)(tids + 4096);
  int*      offs  = (int*)(tws + 4096);
  int*      ptok  = offs + 16;
  int*      sidx  = ptok + 4096;
  int*      tlist = sidx + 4096;                    // 64 ints; [40] = count

  // ---- weight pre-pass: transpose + bf16 convert ----
  tcvt_k<<<dim3(64, 64, 1), 256, 0, stream>>>(wq, wqkvT, 2048, 2048, 0, 0);
  tcvt_k<<<dim3(16, 64, 1), 256, 0, stream>>>(wk, wqkvT + (size_t)2048 * 2048, 2048, 512, 0, 0);
  tcvt_k<<<dim3(16, 64, 1), 256, 0, stream>>>(wv, wqkvT + (size_t)2560 * 2048, 2048, 512, 0, 0);
  tcvt_k<<<dim3(64, 64, 1), 256, 0, stream>>>(wo, woT, 2048, 2048, 0, 0);
  tcvt_k<<<dim3(32, 64, 8), 256, 0, stream>>>(wg, wgT, 2048, 1024, 2048L * 1024, 2048L * 1024);
  tcvt_k<<<dim3(32, 64, 8), 256, 0, stream>>>(wu, wuT, 2048, 1024, 2048L * 1024, 2048L * 1024);
  tcvt_k<<<dim3(64, 32, 8), 256, 0, stream>>>(wd, wdT, 1024, 2048, 1024L * 2048, 1024L * 2048);
  bias_concat_k<<<12, 256, 0, stream>>>(bq, bk, bvp, biasC);

  // ---- layer ----
  rmsnorm_k<<<T_, 256, 0, stream>>>(hs, ln1, XNb);
  // QKV projection, split-K x2 -> bf16 partials (grid.x = n-panel -> XCD pin)
  gemm2_k<false, false, false><<<dim3(24, 32, 1), 256, 0, stream>>>(
      XNb, wqkvT, nullptr, D_, 1024, QKVW_, 0, QKVp, nullptr, (long)T_ * QKVW_,
      nullptr, nullptr, nullptr);
  qkv_prep_k<<<dim3(T_, 6), 256, 0, stream>>>(QKVp, QKVp + (size_t)T_ * QKVW_, biasC, pos,
                                              Qbh, Kbh, Vth);
  attn2_k<<<512, 256, 0, stream>>>(Qbh, Kbh, Vth, ATb);
  // O-projection, split-K x2 -> bf16 partials
  gemm2_k<false, false, false><<<dim3(16, 32, 1), 256, 0, stream>>>(
      ATb, woT, nullptr, NQ_, 1024, D_, 0, Op, nullptr, (long)T_ * D_,
      nullptr, nullptr, nullptr);
  // h = hs + Op0 + Op1 -> out; rmsnorm2 -> XN, XNb
  rms2_comb_k<<<T_, 256, 0, stream>>>(hs, Op, Op + (size_t)T_ * D_, ln2, out, XN, XNb);
  router_k<<<T_, 256, 0, stream>>>(XN, gw, tids, tws);
  route_build_k<<<1, 256, 0, stream>>>(tids, offs, ptok, sidx, tlist);
  // routed gate+up, split-K x2 (DUAL splits grid.x), gather fused via ptok
  gemm2_k<true, true, true><<<dim3(16, 80, 1), 256, 0, stream>>>(
      XNb, wgT, wuT, D_, 1024, I_, 1024L * 2048, Gp, Up, 4194304L, offs, tlist, ptok);
  swiglu_k<<<4096, 256, 0, stream>>>(Gp, Up, FF);
  // routed down-proj, split-K x2 -> bf16 partials (slot rows)
  gemm2_k<true, false, false><<<dim3(16, 80, 1), 256, 0, stream>>>(
      FF, wdT, nullptr, I_, 512, D_, 1024L * 2048, Yp, nullptr, 8388608L, offs, tlist, nullptr);
  moe_combine_k<<<T_, 256, 0, stream>>>(Yp, sidx, tws, out);
}